// Round 12
// baseline (181.131 us; speedup 1.0000x reference)
//
#include <hip/hip_runtime.h>

typedef _Float16 half8 __attribute__((ext_vector_type(8)));
typedef float f32x4 __attribute__((ext_vector_type(4)));

#define T_STEPS 256
#define NB      16
#define NBLOCKS (4096/NB)    // 256 blocks = 1 per CU
#define LOG2E   1.4426950408889634f

// merged activation buffer stride (f16): cols 0..63 = h1, 64..127 = h2.
#define SH 136

__device__ __forceinline__ half8 cvt8s(const float* __restrict__ p, float s) {
    half8 r;
    #pragma unroll
    for (int j = 0; j < 8; ++j) r[j] = (_Float16)(p[j] * s);
    return r;
}

// LDS-only barrier: does NOT drain vmcnt, so global x prefetch stays in flight.
__device__ __forceinline__ void sync_lds() {
    asm volatile("s_waitcnt lgkmcnt(0)" ::: "memory");
    __builtin_amdgcn_s_barrier();
}

// 16 waves/block (1024 thr), 4 waves/SIMD. Waves 0-7: layer 1, 8-15: layer 2.
// KEY: weight rows are PERMUTED so a 16x16 M-tile holds 4 units x 4 gates
// (tile row = 4*unit_local + gate). MFMA C-layout row=4*lb+jj then gives each
// lane all 4 gates of unit U0+lb in acc[0..3] -> lane-local ACT with only
// 2 M-tiles of weights per wave (~80 VGPR total, fits 4 waves/SIMD @128 cap).
__global__ __launch_bounds__(1024, 4)
void lstm_v12(const float* __restrict__ x,
              const float* __restrict__ Wih0, const float* __restrict__ Whh0,
              const float* __restrict__ bih0, const float* __restrict__ bhh0,
              const float* __restrict__ Wih1, const float* __restrict__ Whh1,
              const float* __restrict__ bih1, const float* __restrict__ bhh1,
              const float* __restrict__ Wout, const float* __restrict__ bout,
              float* __restrict__ out)
{
    __shared__ _Float16 Hb[2][16][SH];

    const int tid  = threadIdx.x;
    const int w    = tid >> 6;
    const bool isL1 = (w < 8);
    const int wq   = w & 7;             // wave index within its layer group
    const int l    = tid & 63;
    const int ln   = l & 15;            // A row-in-tile / B col (batch)
    const int lb   = l >> 4;            // k sub-block / C row group
    const int U0   = 8 * wq;            // tile0 units U0..U0+3, tile1 U0+4..U0+7
    const int gb0  = blockIdx.x * NB;

    // A-row decode: tile row ln = 4*unit_local + gate
    const int qa = ln & 3;              // gate type of this lane's A row
    const int ua = ln >> 2;             // unit offset within tile
    const float sa = (qa == 2) ? 2.f * LOG2E : -LOG2E;   // g-gate: +2log2e

    // ---- weights: 2 tiles/wave, register-resident, scale pre-folded ----
    // L1: wa[t][0] = x K-slice, wa[t][1..2] = h1 K-slices; L2: wa[t][0..3].
    half8 wa[2][4];
    f32x4 bv[2];
    if (isL1) {
        #pragma unroll
        for (int t = 0; t < 2; ++t) {
            const int gr = 64 * qa + U0 + 4 * t + ua;     // permuted W row
            wa[t][0] = cvt8s(Wih0 + gr * 32 + 8 * lb, sa);
            wa[t][1] = cvt8s(Whh0 + gr * 64 + 8 * lb, sa);
            wa[t][2] = cvt8s(Whh0 + gr * 64 + 32 + 8 * lb, sa);
            #pragma unroll
            for (int jj = 0; jj < 4; ++jj) {              // C row 4lb+jj
                const int g = 64 * jj + U0 + 4 * t + lb;  // gate jj, unit U0+4t+lb
                const float s = (jj == 2) ? 2.f * LOG2E : -LOG2E;
                bv[t][jj] = (bih0[g] + bhh0[g]) * s;
            }
        }
    } else {
        #pragma unroll
        for (int t = 0; t < 2; ++t) {
            const int gr = 64 * qa + U0 + 4 * t + ua;
            #pragma unroll
            for (int ks = 0; ks < 4; ++ks) {
                const int c0 = 32 * ks + 8 * lb;
                const float* p = (c0 < 64) ? (Wih1 + gr * 64 + c0)
                                           : (Whh1 + gr * 64 + (c0 - 64));
                wa[t][ks] = cvt8s(p, sa);
            }
            #pragma unroll
            for (int jj = 0; jj < 4; ++jj) {
                const int g = 64 * jj + U0 + 4 * t + lb;
                const float s = (jj == 2) ? 2.f * LOG2E : -LOG2E;
                bv[t][jj] = (bih1[g] + bhh1[g]) * s;
            }
        }
    }

    float cst0 = 0.f, cst1 = 0.f;       // c state: one unit per tile per lane

    // ---- zero LDS (h1(-1)=h2(-1)=0) ----
    {
        unsigned int* z = (unsigned int*)Hb;
        for (int i = tid; i < (int)(sizeof(Hb) / 4); i += 1024) z[i] = 0u;
    }

    // ---- L1 x path: lane owns x[batch gb0+ln][t][8lb..8lb+7]; 2-deep ----
    // (all 8 L1 waves read the same 2KB/step -> L1-cache broadcast)
    const float* xb = x + (long)(gb0 + ln) * T_STEPS * 32 + 8 * lb;
    f32x4 xr0 = {0.f,0.f,0.f,0.f}, xr1 = {0.f,0.f,0.f,0.f};
    f32x4 gxA[2], gxB[2];
    if (isL1) {
        const f32x4 x0a = *(const f32x4*)(xb);
        const f32x4 x0b = *(const f32x4*)(xb + 4);
        half8 xf;
        #pragma unroll
        for (int j = 0; j < 4; ++j) { xf[j] = (_Float16)x0a[j]; xf[4+j] = (_Float16)x0b[j]; }
        gxA[0] = __builtin_amdgcn_mfma_f32_16x16x32_f16(wa[0][0], xf, bv[0], 0, 0, 0);
        gxA[1] = __builtin_amdgcn_mfma_f32_16x16x32_f16(wa[1][0], xf, bv[1], 0, 0, 0);
        xr0 = *(const f32x4*)(xb + 32);      // x(1)
        xr1 = *(const f32x4*)(xb + 36);
    }
    sync_lds();

// per-unit LSTM cell update (lane holds gates i,f,g,o of ONE unit in AV[0..3],
// pre-scaled): ei=e^{-i}, ef=e^{-f}, Eg=e^{2g}, eo=e^{-o}
#define ACT_U(AV, CS, HOUT)                                                    \
    {                                                                          \
        const float ei = __builtin_amdgcn_exp2f(AV[0]);                        \
        const float ef = __builtin_amdgcn_exp2f(AV[1]);                        \
        const float Eg = __builtin_amdgcn_exp2f(AV[2]);                        \
        const float eo = __builtin_amdgcn_exp2f(AV[3]);                        \
        const float ti = 1.f + ei, tf = 1.f + ef, tg = 1.f + Eg;               \
        const float pig = ti * tg;                                             \
        const float num = fmaf(Eg - 1.f, tf, (CS) * pig);                      \
        const float c   = num * __builtin_amdgcn_rcpf(pig * tf);               \
        (CS) = c;                                                              \
        const float Ec  = __builtin_amdgcn_exp2f(fminf((2.f * LOG2E) * c, 120.f)); \
        HOUT = (_Float16)((Ec - 1.f) *                                         \
               __builtin_amdgcn_rcpf((1.f + eo) * (1.f + Ec)));                \
    }

#define STEP(J, P, GXC, GXN)                                                   \
    do {                                                                       \
        if (isL1 && (J) < T_STEPS) {                                           \
            const half8 bf0 = *(const half8*)&Hb[P][ln][8 * lb];               \
            const half8 bf1 = *(const half8*)&Hb[P][ln][32 + 8 * lb];          \
            half8 xf;                                                          \
            _Pragma("unroll")                                                  \
            for (int j = 0; j < 4; ++j) { xf[j] = (_Float16)xr0[j]; xf[4+j] = (_Float16)xr1[j]; } \
            GXN[0] = __builtin_amdgcn_mfma_f32_16x16x32_f16(wa[0][0], xf, bv[0], 0, 0, 0); \
            GXN[1] = __builtin_amdgcn_mfma_f32_16x16x32_f16(wa[1][0], xf, bv[1], 0, 0, 0); \
            { const int jn = ((J) + 2 < T_STEPS) ? (J) + 2 : T_STEPS - 1;      \
              xr0 = *(const f32x4*)(xb + jn * 32);                             \
              xr1 = *(const f32x4*)(xb + jn * 32 + 4); }                       \
            __builtin_amdgcn_s_setprio(1);                                     \
            GXC[0] = __builtin_amdgcn_mfma_f32_16x16x32_f16(wa[0][1], bf0, GXC[0], 0, 0, 0); \
            GXC[1] = __builtin_amdgcn_mfma_f32_16x16x32_f16(wa[1][1], bf0, GXC[1], 0, 0, 0); \
            GXC[0] = __builtin_amdgcn_mfma_f32_16x16x32_f16(wa[0][2], bf1, GXC[0], 0, 0, 0); \
            GXC[1] = __builtin_amdgcn_mfma_f32_16x16x32_f16(wa[1][2], bf1, GXC[1], 0, 0, 0); \
            __builtin_amdgcn_s_setprio(0);                                     \
            _Float16 h0v, h1v;                                                 \
            ACT_U(GXC[0], cst0, h0v) ACT_U(GXC[1], cst1, h1v)                  \
            Hb[1 - (P)][ln][U0 + lb]     = h0v;                                \
            Hb[1 - (P)][ln][U0 + 4 + lb] = h1v;                                \
        }                                                                      \
        if (!isL1 && (J) >= 1 && (J) <= T_STEPS) {                             \
            const half8 bf0 = *(const half8*)&Hb[P][ln][8 * lb];               \
            const half8 bf1 = *(const half8*)&Hb[P][ln][32 + 8 * lb];          \
            const half8 bf2 = *(const half8*)&Hb[P][ln][64 + 8 * lb];          \
            const half8 bf3 = *(const half8*)&Hb[P][ln][96 + 8 * lb];          \
            f32x4 a0 = bv[0], a1 = bv[1];                                      \
            __builtin_amdgcn_s_setprio(1);                                     \
            a0 = __builtin_amdgcn_mfma_f32_16x16x32_f16(wa[0][0], bf0, a0, 0, 0, 0); \
            a1 = __builtin_amdgcn_mfma_f32_16x16x32_f16(wa[1][0], bf0, a1, 0, 0, 0); \
            a0 = __builtin_amdgcn_mfma_f32_16x16x32_f16(wa[0][1], bf1, a0, 0, 0, 0); \
            a1 = __builtin_amdgcn_mfma_f32_16x16x32_f16(wa[1][1], bf1, a1, 0, 0, 0); \
            a0 = __builtin_amdgcn_mfma_f32_16x16x32_f16(wa[0][2], bf2, a0, 0, 0, 0); \
            a1 = __builtin_amdgcn_mfma_f32_16x16x32_f16(wa[1][2], bf2, a1, 0, 0, 0); \
            a0 = __builtin_amdgcn_mfma_f32_16x16x32_f16(wa[0][3], bf3, a0, 0, 0, 0); \
            a1 = __builtin_amdgcn_mfma_f32_16x16x32_f16(wa[1][3], bf3, a1, 0, 0, 0); \
            __builtin_amdgcn_s_setprio(0);                                     \
            _Float16 h0v, h1v;                                                 \
            ACT_U(a0, cst0, h0v) ACT_U(a1, cst1, h1v)                          \
            Hb[1 - (P)][ln][64 + U0 + lb]     = h0v;                           \
            Hb[1 - (P)][ln][64 + U0 + 4 + lb] = h1v;                           \
        }                                                                      \
        sync_lds();                                                            \
    } while (0)

    // intervals j=0..256: L1 active j<256 computing h1(j); L2 (lag 1) active
    // 1<=j<=256 computing h2(j-1). h2(255) written at j=256 (P=0) -> Hb[1].
    for (int jj = 0; jj < T_STEPS; jj += 2) {
        STEP(jj, 0, gxA, gxB);
        STEP(jj + 1, 1, gxB, gxA);
    }
    STEP(T_STEPS, 0, gxA, gxB);

    // ---- output head: out[b] = h2(255) . Wout + bout ----
    if (tid < NB) {
        float s = bout[0];
        #pragma unroll
        for (int u8 = 0; u8 < 8; ++u8) {
            const half8 hv = *(const half8*)&Hb[1][tid][64 + 8 * u8];
            #pragma unroll
            for (int j = 0; j < 8; ++j)
                s += (float)hv[j] * Wout[8 * u8 + j];
        }
        out[gb0 + tid] = s;
    }
}

extern "C" void kernel_launch(void* const* d_in, const int* in_sizes, int n_in,
                              void* d_out, int out_size, void* d_ws, size_t ws_size,
                              hipStream_t stream) {
    const float* x    = (const float*)d_in[0];
    const float* Wih0 = (const float*)d_in[1];
    const float* Whh0 = (const float*)d_in[2];
    const float* bih0 = (const float*)d_in[3];
    const float* bhh0 = (const float*)d_in[4];
    const float* Wih1 = (const float*)d_in[5];
    const float* Whh1 = (const float*)d_in[6];
    const float* bih1 = (const float*)d_in[7];
    const float* bhh1 = (const float*)d_in[8];
    const float* Wout = (const float*)d_in[9];
    const float* bout = (const float*)d_in[10];

    hipLaunchKernelGGL(lstm_v12, dim3(NBLOCKS), dim3(1024), 0, stream,
                       x, Wih0, Whh0, bih0, bhh0,
                       Wih1, Whh1, bih1, bhh1, Wout, bout,
                       (float*)d_out);
}